// Round 12
// baseline (875.065 us; speedup 1.0000x reference)
//
#include <hip/hip_runtime.h>
#include <hip/hip_bf16.h>

#define M_TOK 16384
#define K_DIM 1024
#define E_NUM 8
#define N_DIM 5632
#define HALF_N 2816
#define TOPK 2
#define NPAIR (M_TOK * TOPK)     // 32768
#define BM 128
#define BH1 128                  // gemm1 h-cols per block
#define BN2 256                  // gemm2 k-cols per block
#define NDESC (NPAIR / BM + E_NUM)  // 264
#define NHB1 (HALF_N / BH1)      // 22
#define NNB2 (K_DIM / BN2)       // 4

typedef short s16x4 __attribute__((ext_vector_type(4)));
typedef short s16x8 __attribute__((ext_vector_type(8)));
typedef float f32x4 __attribute__((ext_vector_type(4)));

__device__ __forceinline__ short f2bf(float f) {
  union { __hip_bfloat16 h; short s; } c;
  c.h = __float2bfloat16(f);
  return c.s;
}

__device__ __forceinline__ float bf2f(unsigned short s) {
  union { float f; unsigned u; } c;
  c.u = ((unsigned)s) << 16;
  return c.f;
}

__device__ __forceinline__ void gload_lds16(const void* g, void* l) {
  __builtin_amdgcn_global_load_lds(
      (const __attribute__((address_space(1))) unsigned int*)g,
      (__attribute__((address_space(3))) unsigned int*)l, 16, 0, 0);
}

// bijective XCD-aware work remap (m204): consecutive work indices land on one XCD
__device__ __forceinline__ int xcd_work(int bid, int nwg) {
  const int xcd = bid & 7, loc = bid >> 3;
  const int q = nwg >> 3, r = nwg & 7;
  return (xcd < r ? xcd * (q + 1) : r * (q + 1) + (xcd - r) * q) + loc;
}

// ---------------- conversion ----------------
__global__ void cvt_f32_bf16_k(const float4* __restrict__ src,
                               s16x4* __restrict__ dst, int n4) {
  int i = blockIdx.x * blockDim.x + threadIdx.x;
  int stride = gridDim.x * blockDim.x;
  for (; i < n4; i += stride) {
    float4 f = src[i];
    s16x4 o = { f2bf(f.x), f2bf(f.y), f2bf(f.z), f2bf(f.w) };
    dst[i] = o;
  }
}

// ---------------- routing (two-level, ~1k global atomics total) ----------------
__global__ void moe_count(const int* __restrict__ ids, int* __restrict__ cnt) {
  const int p = blockIdx.x * 256 + threadIdx.x;
  const int e = ids[p];
  const int lane = threadIdx.x & 63;
  __shared__ int h[E_NUM];
  if (threadIdx.x < E_NUM) h[threadIdx.x] = 0;
  __syncthreads();
#pragma unroll
  for (int ex = 0; ex < E_NUM; ++ex) {
    unsigned long long m = __ballot(e == ex);
    if (lane == 0 && m) atomicAdd(&h[ex], __popcll(m));
  }
  __syncthreads();
  if (threadIdx.x < E_NUM) atomicAdd(&cnt[threadIdx.x], h[threadIdx.x]);
}

__global__ void moe_build(const int* __restrict__ cnt, int* __restrict__ offs,
                          int4* __restrict__ desc) {
  if (blockIdx.x == 0 && threadIdx.x == 0) {
    int o = 0, d = 0;
    for (int e = 0; e < E_NUM; ++e) {
      offs[e] = o;
      int end = o + cnt[e];
      for (int s = o; s < end; s += BM) desc[d++] = make_int4(e, s, end, 0);
      o = end;
    }
    offs[E_NUM] = o;
    while (d < NDESC) desc[d++] = make_int4(-1, 0, 0, 0);
  }
}

__global__ void moe_scatter(const int* __restrict__ ids, const float* __restrict__ tw,
                            const int* __restrict__ offs, int* __restrict__ fill,
                            int* __restrict__ tok, float* __restrict__ wgt,
                            int* __restrict__ inv) {
  const int p = blockIdx.x * 256 + threadIdx.x;
  const int e = ids[p];
  const int lane = threadIdx.x & 63;
  const int w = threadIdx.x >> 6;  // 0..3
  __shared__ int wcnt[4][E_NUM];
  __shared__ int wpre[4][E_NUM];
  __shared__ int base[E_NUM];
  const unsigned long long lt = (1ull << lane) - 1ull;
  int myrank = 0;
#pragma unroll
  for (int ex = 0; ex < E_NUM; ++ex) {
    unsigned long long m = __ballot(e == ex);
    if (e == ex) myrank = (int)__popcll(m & lt);
    if (lane == 0) wcnt[w][ex] = (int)__popcll(m);
  }
  __syncthreads();
  if (threadIdx.x < E_NUM) {
    const int ex = threadIdx.x;
    int s = 0;
#pragma unroll
    for (int ww = 0; ww < 4; ++ww) { wpre[ww][ex] = s; s += wcnt[ww][ex]; }
    base[ex] = atomicAdd(&fill[ex], s);
  }
  __syncthreads();
  const int pos = offs[e] + base[e] + wpre[w][e] + myrank;
  tok[pos] = p >> 1;
  wgt[pos] = tw[p];
  inv[p] = pos;
}

// gather hidden rows into expert-sorted order, fp32 -> bf16
__global__ void moe_gather(const float* __restrict__ hs, const int* __restrict__ tok,
                           unsigned short* __restrict__ hsb) {
  const int pos = blockIdx.x;
  const int m = tok[pos];
  const int t = threadIdx.x;  // 128 threads * 8 elems = 1024
  const float4* s = (const float4*)(hs + (size_t)m * K_DIM) + t * 2;
  const float4 a = s[0], b = s[1];
  s16x8 o = { f2bf(a.x), f2bf(a.y), f2bf(a.z), f2bf(a.w),
              f2bf(b.x), f2bf(b.y), f2bf(b.z), f2bf(b.w) };
  *(s16x8*)(hsb + (size_t)pos * K_DIM + t * 8) = o;
}

// ---------------- GEMM1: h2 = silu(A@Wg^T) * (A@Wu^T) ----------------
// T3-minimum 2-phase overlap: BK=32, double-buffered (48 KB total, occupancy
// unchanged), per tile {STAGE(next buf) -> ds_read+MFMA(cur) -> syncthreads}.
// Staging latency drains under the MFMA cluster; ONE barrier per K-tile.
// Swizzle: LDS[r][c] = src chunk c^(r&3) (4 chunks/row), read with same XOR.
__launch_bounds__(512)
__global__ void moe_gemm1(const unsigned short* __restrict__ hsb,
                          const unsigned short* __restrict__ w1b,
                          const int4* __restrict__ desc,
                          unsigned short* __restrict__ h2) {
  const int work = xcd_work(blockIdx.x, NHB1 * NDESC);
  const int di = work / NHB1;    // desc-major (proven r7 mapping)
  const int hb = work - di * NHB1;
  const int4 d = desc[di];
  const int e = d.x;
  if (e < 0) return;
  const int pos0 = d.y, eend = d.z;
  const int h0 = hb * BH1;

  __shared__ __align__(16) unsigned short As[2][BM * 32];    // 16 KB
  __shared__ __align__(16) unsigned short Gs[2][BH1 * 32];   // 16 KB
  __shared__ __align__(16) unsigned short Us[2][BH1 * 32];   // 16 KB

  const int tid = threadIdx.x;
  const int lane = tid & 63;
  const int wid = tid >> 6;     // 0..7
  const int wr = wid >> 2;      // 0..1 (64-row group)
  const int wc = wid & 3;       // 0..3 (32-col group)
  const int fr = lane & 15;
  const int fq = lane >> 4;

  // staging: granule tid -> row sr = tid>>2, chunk c = tid&3, src chunk c^(sr&3)
  const int sr = tid >> 2;
  const int sc8 = (((tid & 3) ^ (sr & 3)) << 3);
  const unsigned short* Asrc = hsb + ((size_t)(pos0 + sr)) * K_DIM + sc8;
  const unsigned short* Gsrc = w1b + ((size_t)e * N_DIM + h0 + sr) * K_DIM + sc8;
  const unsigned short* Usrc = Gsrc + (size_t)HALF_N * K_DIM;
  const int ldst = tid * 8;

  f32x4 accg[4][2], accu[4][2];
  const f32x4 z = {0.f, 0.f, 0.f, 0.f};
#pragma unroll
  for (int i = 0; i < 4; ++i)
#pragma unroll
    for (int j = 0; j < 2; ++j) { accg[i][j] = z; accu[i][j] = z; }

  // read-side: fragment row R (R&3 == fr&3), chunk fq -> LDS chunk fq^(fr&3)
  const int coff = ((fq ^ (fr & 3)) << 3);

  const int NT = K_DIM / 32;  // 32
  {
    gload_lds16(Asrc, &As[0][ldst]);
    gload_lds16(Gsrc, &Gs[0][ldst]);
    gload_lds16(Usrc, &Us[0][ldst]);
  }
  __syncthreads();

  for (int kt = 0; kt < NT; ++kt) {
    const int b = kt & 1;
    if (kt + 1 < NT) {
      const int k0 = (kt + 1) * 32;
      gload_lds16(Asrc + k0, &As[b ^ 1][ldst]);
      gload_lds16(Gsrc + k0, &Gs[b ^ 1][ldst]);
      gload_lds16(Usrc + k0, &Us[b ^ 1][ldst]);
    }
    s16x8 af[4], gf[2], uf[2];
#pragma unroll
    for (int i = 0; i < 4; ++i)
      af[i] = *(const s16x8*)&As[b][(64 * wr + 16 * i + fr) * 32 + coff];
#pragma unroll
    for (int j = 0; j < 2; ++j) {
      const int off = (32 * wc + 16 * j + fr) * 32 + coff;
      gf[j] = *(const s16x8*)&Gs[b][off];
      uf[j] = *(const s16x8*)&Us[b][off];
    }
#pragma unroll
    for (int i = 0; i < 4; ++i)
#pragma unroll
      for (int j = 0; j < 2; ++j) {
        accg[i][j] = __builtin_amdgcn_mfma_f32_16x16x32_bf16(af[i], gf[j], accg[i][j], 0, 0, 0);
        accu[i][j] = __builtin_amdgcn_mfma_f32_16x16x32_bf16(af[i], uf[j], accu[i][j], 0, 0, 0);
      }
    __syncthreads();   // drains my stage loads (vmcnt 0) + joins readers of b
  }

  const int vlim = eend - pos0;
#pragma unroll
  for (int i = 0; i < 4; ++i) {
#pragma unroll
    for (int rr = 0; rr < 4; ++rr) {
      const int row = 64 * wr + 16 * i + fq * 4 + rr;
      if (row < vlim) {
        unsigned short* dst = h2 + (size_t)(pos0 + row) * HALF_N + h0 + 32 * wc;
#pragma unroll
        for (int j = 0; j < 2; ++j) {
          const float g = accg[i][j][rr];
          const float u = accu[i][j][rr];
          const float sg = g / (1.0f + __expf(-g));
          __builtin_nontemporal_store((unsigned short)f2bf(sg * u), dst + 16 * j + fr);
        }
      }
    }
  }
}

// ---------------- GEMM2: opair[pos] = wgt[pos] * (h2[pos] @ W2^T) ----------------
// same T3-minimum 2-phase transformation: BK=32, double-buffered (48 KB).
__launch_bounds__(512)
__global__ void moe_gemm2(const unsigned short* __restrict__ h2,
                          const unsigned short* __restrict__ w2b,
                          const int4* __restrict__ desc,
                          const float* __restrict__ wgt,
                          unsigned short* __restrict__ opair) {
  const int work = xcd_work(blockIdx.x, NNB2 * NDESC);
  const int di = work >> 2;      // desc-major (proven r7 mapping)
  const int nb = work & 3;
  const int4 d = desc[di];
  const int e = d.x;
  if (e < 0) return;
  const int pos0 = d.y, eend = d.z;
  const int n0 = nb * BN2;

  __shared__ __align__(16) unsigned short As[2][BM * 32];    // 16 KB
  __shared__ __align__(16) unsigned short Bs[2][BN2 * 32];   // 32 KB

  const int tid = threadIdx.x;
  const int lane = tid & 63;
  const int wid = tid >> 6;     // 0..7
  const int wr = wid >> 2;      // 0..1 (64-row group)
  const int wc = wid & 3;       // 0..3 (64-col group)
  const int fr = lane & 15;
  const int fq = lane >> 4;

  const int sr = tid >> 2;
  const int sc8 = (((tid & 3) ^ (sr & 3)) << 3);
  const unsigned short* Asrc  = h2 + ((size_t)(pos0 + sr)) * HALF_N + sc8;
  const unsigned short* Bsrc0 = w2b + ((size_t)e * K_DIM + n0 + sr) * HALF_N + sc8;
  const unsigned short* Bsrc1 = Bsrc0 + (size_t)128 * HALF_N;
  const int ldst = tid * 8;

  f32x4 acc[4][4];
  const f32x4 z = {0.f, 0.f, 0.f, 0.f};
#pragma unroll
  for (int i = 0; i < 4; ++i)
#pragma unroll
    for (int j = 0; j < 4; ++j) acc[i][j] = z;

  const int coff = ((fq ^ (fr & 3)) << 3);

  const int NT = HALF_N / 32;  // 88
  {
    gload_lds16(Asrc, &As[0][ldst]);
    gload_lds16(Bsrc0, &Bs[0][ldst]);
    gload_lds16(Bsrc1, &Bs[0][4096 + ldst]);
  }
  __syncthreads();

  for (int ht = 0; ht < NT; ++ht) {
    const int b = ht & 1;
    if (ht + 1 < NT) {
      const int k0 = (ht + 1) * 32;
      gload_lds16(Asrc + k0, &As[b ^ 1][ldst]);
      gload_lds16(Bsrc0 + k0, &Bs[b ^ 1][ldst]);
      gload_lds16(Bsrc1 + k0, &Bs[b ^ 1][4096 + ldst]);
    }
    s16x8 af[4], bf[4];
#pragma unroll
    for (int i = 0; i < 4; ++i)
      af[i] = *(const s16x8*)&As[b][(64 * wr + 16 * i + fr) * 32 + coff];
#pragma unroll
    for (int j = 0; j < 4; ++j)
      bf[j] = *(const s16x8*)&Bs[b][(64 * wc + 16 * j + fr) * 32 + coff];
#pragma unroll
    for (int i = 0; i < 4; ++i)
#pragma unroll
      for (int j = 0; j < 4; ++j)
        acc[i][j] = __builtin_amdgcn_mfma_f32_16x16x32_bf16(af[i], bf[j], acc[i][j], 0, 0, 0);
    __syncthreads();
  }

  const int vlim = eend - pos0;
#pragma unroll
  for (int i = 0; i < 4; ++i) {
#pragma unroll
    for (int rr = 0; rr < 4; ++rr) {
      const int row = 64 * wr + 16 * i + fq * 4 + rr;
      if (row < vlim) {
        const int pos = pos0 + row;
        const float wt = wgt[pos];
        unsigned short* dst = opair + (size_t)pos * K_DIM + n0 + 64 * wc;
#pragma unroll
        for (int j = 0; j < 4; ++j)
          dst[16 * j + fr] = (unsigned short)f2bf(wt * acc[i][j][rr]);
      }
    }
  }
}

// ---------------- combine: out[m] = opair[inv[2m]] + opair[inv[2m+1]] ----------------
__global__ void moe_combine(const unsigned short* __restrict__ opair,
                            const int* __restrict__ inv,
                            float* __restrict__ out) {
  const int m = blockIdx.x;
  const int t = threadIdx.x;  // 128 threads * 8 elems
  const int p0 = inv[2 * m], p1 = inv[2 * m + 1];
  const s16x8 a = *(const s16x8*)&opair[(size_t)p0 * K_DIM + t * 8];
  const s16x8 b = *(const s16x8*)&opair[(size_t)p1 * K_DIM + t * 8];
  f32x4 o0, o1;
  o0[0] = bf2f((unsigned short)a[0]) + bf2f((unsigned short)b[0]);
  o0[1] = bf2f((unsigned short)a[1]) + bf2f((unsigned short)b[1]);
  o0[2] = bf2f((unsigned short)a[2]) + bf2f((unsigned short)b[2]);
  o0[3] = bf2f((unsigned short)a[3]) + bf2f((unsigned short)b[3]);
  o1[0] = bf2f((unsigned short)a[4]) + bf2f((unsigned short)b[4]);
  o1[1] = bf2f((unsigned short)a[5]) + bf2f((unsigned short)b[5]);
  o1[2] = bf2f((unsigned short)a[6]) + bf2f((unsigned short)b[6]);
  o1[3] = bf2f((unsigned short)a[7]) + bf2f((unsigned short)b[7]);
  f32x4* dst = (f32x4*)(out + (size_t)m * K_DIM + t * 8);
  __builtin_nontemporal_store(o0, dst);       // final output, never re-read
  __builtin_nontemporal_store(o1, dst + 1);
}

__global__ void sentinel_k(float* o) { o[0] = 1.0e9f; }

extern "C" void kernel_launch(void* const* d_in, const int* in_sizes, int n_in,
                              void* d_out, int out_size, void* d_ws, size_t ws_size,
                              hipStream_t stream) {
  const float* hs = (const float*)d_in[0];
  const float* w1 = (const float*)d_in[1];
  const float* w2 = (const float*)d_in[2];
  const float* tw = (const float*)d_in[3];
  const int* ids = (const int*)d_in[4];
  float* out = (float*)d_out;

  char* p = (char*)d_ws;
  auto carve = [&](size_t bytes) {
    char* r = p;
    p += (bytes + 255) & ~(size_t)255;
    return r;
  };
  unsigned short* w1b = (unsigned short*)carve((size_t)E_NUM * N_DIM * K_DIM * 2);
  unsigned short* w2b = (unsigned short*)carve((size_t)E_NUM * K_DIM * HALF_N * 2);
  unsigned short* hsb = (unsigned short*)carve((size_t)(NPAIR + BM) * K_DIM * 2);
  unsigned short* h2  = (unsigned short*)carve((size_t)(NPAIR + BM) * HALF_N * 2);
  int*   tok  = (int*)carve(NPAIR * 4);
  float* wgt  = (float*)carve(NPAIR * 4);
  int*   inv  = (int*)carve(NPAIR * 4);
  int*   meta = (int*)carve(1024);
  int4*  desc = (int4*)carve(NDESC * sizeof(int4));
  size_t need = (size_t)(p - (char*)d_ws);

  // opair aliases hsb (hsb dead after gemm1; identical size NPAIR*K_DIM*2)
  unsigned short* opair = hsb;

  if (need > ws_size) {  // unmistakable failure mode if workspace is too small
    hipMemsetAsync(d_out, 0, (size_t)out_size * sizeof(float), stream);
    sentinel_k<<<1, 1, 0, stream>>>(out);
    return;
  }

  int* cnt  = meta;        // 8 ints
  int* fill = meta + 64;   // 8 ints
  int* offs = meta + 128;  // 9 ints

  hipMemsetAsync(meta, 0, 1024, stream);

  cvt_f32_bf16_k<<<2048, 256, 0, stream>>>(
      (const float4*)w1, (s16x4*)w1b, (int)((size_t)E_NUM * N_DIM * K_DIM / 4));
  cvt_f32_bf16_k<<<2048, 256, 0, stream>>>(
      (const float4*)w2, (s16x4*)w2b, (int)((size_t)E_NUM * K_DIM * HALF_N / 4));
  moe_count<<<NPAIR / 256, 256, 0, stream>>>(ids, cnt);
  moe_build<<<1, 64, 0, stream>>>(cnt, offs, desc);
  moe_scatter<<<NPAIR / 256, 256, 0, stream>>>(ids, tw, offs, fill, tok, wgt, inv);
  moe_gather<<<NPAIR, 128, 0, stream>>>(hs, tok, hsb);
  moe_gemm1<<<NHB1 * NDESC, 512, 0, stream>>>(hsb, w1b, desc, h2);
  moe_gemm2<<<NNB2 * NDESC, 512, 0, stream>>>(h2, w2b, desc, wgt, opair);
  moe_combine<<<M_TOK, 128, 0, stream>>>(opair, inv, out);
}

// Round 13
// 865.437 us; speedup vs baseline: 1.0111x; 1.0111x over previous
//
#include <hip/hip_runtime.h>
#include <hip/hip_bf16.h>

#define M_TOK 16384
#define K_DIM 1024
#define E_NUM 8
#define N_DIM 5632
#define HALF_N 2816
#define TOPK 2
#define NPAIR (M_TOK * TOPK)     // 32768
#define BM 128
#define BH1 128                  // gemm1 h-cols per block
#define BN2 256                  // gemm2 k-cols per block
#define NDESC (NPAIR / BM + E_NUM)  // 264
#define NHB1 (HALF_N / BH1)      // 22
#define NNB2 (K_DIM / BN2)       // 4

typedef short s16x4 __attribute__((ext_vector_type(4)));
typedef short s16x8 __attribute__((ext_vector_type(8)));
typedef float f32x4 __attribute__((ext_vector_type(4)));

__device__ __forceinline__ short f2bf(float f) {
  union { __hip_bfloat16 h; short s; } c;
  c.h = __float2bfloat16(f);
  return c.s;
}

__device__ __forceinline__ float bf2f(unsigned short s) {
  union { float f; unsigned u; } c;
  c.u = ((unsigned)s) << 16;
  return c.f;
}

__device__ __forceinline__ void gload_lds16(const void* g, void* l) {
  __builtin_amdgcn_global_load_lds(
      (const __attribute__((address_space(1))) unsigned int*)g,
      (__attribute__((address_space(3))) unsigned int*)l, 16, 0, 0);
}

// bijective XCD-aware work remap (m204): consecutive work indices land on one XCD
__device__ __forceinline__ int xcd_work(int bid, int nwg) {
  const int xcd = bid & 7, loc = bid >> 3;
  const int q = nwg >> 3, r = nwg & 7;
  return (xcd < r ? xcd * (q + 1) : r * (q + 1) + (xcd - r) * q) + loc;
}

// ---------------- conversion ----------------
__global__ void cvt_f32_bf16_k(const float4* __restrict__ src,
                               s16x4* __restrict__ dst, int n4) {
  int i = blockIdx.x * blockDim.x + threadIdx.x;
  int stride = gridDim.x * blockDim.x;
  for (; i < n4; i += stride) {
    float4 f = src[i];
    s16x4 o = { f2bf(f.x), f2bf(f.y), f2bf(f.z), f2bf(f.w) };
    dst[i] = o;
  }
}

// ---------------- routing (two-level, ~1k global atomics total) ----------------
__global__ void moe_count(const int* __restrict__ ids, int* __restrict__ cnt) {
  const int p = blockIdx.x * 256 + threadIdx.x;
  const int e = ids[p];
  const int lane = threadIdx.x & 63;
  __shared__ int h[E_NUM];
  if (threadIdx.x < E_NUM) h[threadIdx.x] = 0;
  __syncthreads();
#pragma unroll
  for (int ex = 0; ex < E_NUM; ++ex) {
    unsigned long long m = __ballot(e == ex);
    if (lane == 0 && m) atomicAdd(&h[ex], __popcll(m));
  }
  __syncthreads();
  if (threadIdx.x < E_NUM) atomicAdd(&cnt[threadIdx.x], h[threadIdx.x]);
}

__global__ void moe_build(const int* __restrict__ cnt, int* __restrict__ offs,
                          int4* __restrict__ desc) {
  if (blockIdx.x == 0 && threadIdx.x == 0) {
    int o = 0, d = 0;
    for (int e = 0; e < E_NUM; ++e) {
      offs[e] = o;
      int end = o + cnt[e];
      for (int s = o; s < end; s += BM) desc[d++] = make_int4(e, s, end, 0);
      o = end;
    }
    offs[E_NUM] = o;
    while (d < NDESC) desc[d++] = make_int4(-1, 0, 0, 0);
  }
}

__global__ void moe_scatter(const int* __restrict__ ids, const float* __restrict__ tw,
                            const int* __restrict__ offs, int* __restrict__ fill,
                            int* __restrict__ tok, float* __restrict__ wgt,
                            int* __restrict__ inv) {
  const int p = blockIdx.x * 256 + threadIdx.x;
  const int e = ids[p];
  const int lane = threadIdx.x & 63;
  const int w = threadIdx.x >> 6;  // 0..3
  __shared__ int wcnt[4][E_NUM];
  __shared__ int wpre[4][E_NUM];
  __shared__ int base[E_NUM];
  const unsigned long long lt = (1ull << lane) - 1ull;
  int myrank = 0;
#pragma unroll
  for (int ex = 0; ex < E_NUM; ++ex) {
    unsigned long long m = __ballot(e == ex);
    if (e == ex) myrank = (int)__popcll(m & lt);
    if (lane == 0) wcnt[w][ex] = (int)__popcll(m);
  }
  __syncthreads();
  if (threadIdx.x < E_NUM) {
    const int ex = threadIdx.x;
    int s = 0;
#pragma unroll
    for (int ww = 0; ww < 4; ++ww) { wpre[ww][ex] = s; s += wcnt[ww][ex]; }
    base[ex] = atomicAdd(&fill[ex], s);
  }
  __syncthreads();
  const int pos = offs[e] + base[e] + wpre[w][e] + myrank;
  tok[pos] = p >> 1;
  wgt[pos] = tw[p];
  inv[p] = pos;
}

// gather hidden rows into expert-sorted order, fp32 -> bf16
__global__ void moe_gather(const float* __restrict__ hs, const int* __restrict__ tok,
                           unsigned short* __restrict__ hsb) {
  const int pos = blockIdx.x;
  const int m = tok[pos];
  const int t = threadIdx.x;  // 128 threads * 8 elems = 1024
  const float4* s = (const float4*)(hs + (size_t)m * K_DIM) + t * 2;
  const float4 a = s[0], b = s[1];
  s16x8 o = { f2bf(a.x), f2bf(a.y), f2bf(a.z), f2bf(a.w),
              f2bf(b.x), f2bf(b.y), f2bf(b.z), f2bf(b.w) };
  *(s16x8*)(hsb + (size_t)pos * K_DIM + t * 8) = o;
}

// ---------------- GEMM1: h2 = silu(A@Wg^T) * (A@Wu^T) ----------------
// T3-minimum 2-phase overlap (r12 structure) with CORRECTED swizzle key:
// 64B rows wrap banks every 2 rows -> key = (row>>1)&3 (r12's (row&3) gave a
// 4-way conflict, 4.67e7 counts). Staging chunk c -> src chunk c^((r>>1)&3);
// read chunk fq -> LDS chunk fq^((r>>1)&3). Both-sides involution (rule 21).
__launch_bounds__(512)
__global__ void moe_gemm1(const unsigned short* __restrict__ hsb,
                          const unsigned short* __restrict__ w1b,
                          const int4* __restrict__ desc,
                          unsigned short* __restrict__ h2) {
  const int work = xcd_work(blockIdx.x, NHB1 * NDESC);
  const int di = work / NHB1;    // desc-major (proven r7 mapping)
  const int hb = work - di * NHB1;
  const int4 d = desc[di];
  const int e = d.x;
  if (e < 0) return;
  const int pos0 = d.y, eend = d.z;
  const int h0 = hb * BH1;

  __shared__ __align__(16) unsigned short As[2][BM * 32];    // 16 KB
  __shared__ __align__(16) unsigned short Gs[2][BH1 * 32];   // 16 KB
  __shared__ __align__(16) unsigned short Us[2][BH1 * 32];   // 16 KB

  const int tid = threadIdx.x;
  const int lane = tid & 63;
  const int wid = tid >> 6;     // 0..7
  const int wr = wid >> 2;      // 0..1 (64-row group)
  const int wc = wid & 3;       // 0..3 (32-col group)
  const int fr = lane & 15;
  const int fq = lane >> 4;

  // staging: granule tid -> row sr = tid>>2, chunk c = tid&3, src chunk c^((sr>>1)&3)
  const int sr = tid >> 2;
  const int sc8 = (((tid & 3) ^ ((sr >> 1) & 3)) << 3);
  const unsigned short* Asrc = hsb + ((size_t)(pos0 + sr)) * K_DIM + sc8;
  const unsigned short* Gsrc = w1b + ((size_t)e * N_DIM + h0 + sr) * K_DIM + sc8;
  const unsigned short* Usrc = Gsrc + (size_t)HALF_N * K_DIM;
  const int ldst = tid * 8;

  f32x4 accg[4][2], accu[4][2];
  const f32x4 z = {0.f, 0.f, 0.f, 0.f};
#pragma unroll
  for (int i = 0; i < 4; ++i)
#pragma unroll
    for (int j = 0; j < 2; ++j) { accg[i][j] = z; accu[i][j] = z; }

  // read-side: fragment row R has (R>>1)&3 == (fr>>1)&3 (row bases are mult of 16)
  const int coff = ((fq ^ ((fr >> 1) & 3)) << 3);

  const int NT = K_DIM / 32;  // 32
  {
    gload_lds16(Asrc, &As[0][ldst]);
    gload_lds16(Gsrc, &Gs[0][ldst]);
    gload_lds16(Usrc, &Us[0][ldst]);
  }
  __syncthreads();

  for (int kt = 0; kt < NT; ++kt) {
    const int b = kt & 1;
    if (kt + 1 < NT) {
      const int k0 = (kt + 1) * 32;
      gload_lds16(Asrc + k0, &As[b ^ 1][ldst]);
      gload_lds16(Gsrc + k0, &Gs[b ^ 1][ldst]);
      gload_lds16(Usrc + k0, &Us[b ^ 1][ldst]);
    }
    s16x8 af[4], gf[2], uf[2];
#pragma unroll
    for (int i = 0; i < 4; ++i)
      af[i] = *(const s16x8*)&As[b][(64 * wr + 16 * i + fr) * 32 + coff];
#pragma unroll
    for (int j = 0; j < 2; ++j) {
      const int off = (32 * wc + 16 * j + fr) * 32 + coff;
      gf[j] = *(const s16x8*)&Gs[b][off];
      uf[j] = *(const s16x8*)&Us[b][off];
    }
#pragma unroll
    for (int i = 0; i < 4; ++i)
#pragma unroll
      for (int j = 0; j < 2; ++j) {
        accg[i][j] = __builtin_amdgcn_mfma_f32_16x16x32_bf16(af[i], gf[j], accg[i][j], 0, 0, 0);
        accu[i][j] = __builtin_amdgcn_mfma_f32_16x16x32_bf16(af[i], uf[j], accu[i][j], 0, 0, 0);
      }
    __syncthreads();   // drains my stage loads (vmcnt 0) + joins readers of b
  }

  const int vlim = eend - pos0;
#pragma unroll
  for (int i = 0; i < 4; ++i) {
#pragma unroll
    for (int rr = 0; rr < 4; ++rr) {
      const int row = 64 * wr + 16 * i + fq * 4 + rr;
      if (row < vlim) {
        unsigned short* dst = h2 + (size_t)(pos0 + row) * HALF_N + h0 + 32 * wc;
#pragma unroll
        for (int j = 0; j < 2; ++j) {
          const float g = accg[i][j][rr];
          const float u = accu[i][j][rr];
          const float sg = g / (1.0f + __expf(-g));
          __builtin_nontemporal_store((unsigned short)f2bf(sg * u), dst + 16 * j + fr);
        }
      }
    }
  }
}

// ---------------- GEMM2: opair[pos] = wgt[pos] * (h2[pos] @ W2^T) ----------------
// same corrected-swizzle 2-phase transformation.
__launch_bounds__(512)
__global__ void moe_gemm2(const unsigned short* __restrict__ h2,
                          const unsigned short* __restrict__ w2b,
                          const int4* __restrict__ desc,
                          const float* __restrict__ wgt,
                          unsigned short* __restrict__ opair) {
  const int work = xcd_work(blockIdx.x, NNB2 * NDESC);
  const int di = work >> 2;      // desc-major (proven r7 mapping)
  const int nb = work & 3;
  const int4 d = desc[di];
  const int e = d.x;
  if (e < 0) return;
  const int pos0 = d.y, eend = d.z;
  const int n0 = nb * BN2;

  __shared__ __align__(16) unsigned short As[2][BM * 32];    // 16 KB
  __shared__ __align__(16) unsigned short Bs[2][BN2 * 32];   // 32 KB

  const int tid = threadIdx.x;
  const int lane = tid & 63;
  const int wid = tid >> 6;     // 0..7
  const int wr = wid >> 2;      // 0..1 (64-row group)
  const int wc = wid & 3;       // 0..3 (64-col group)
  const int fr = lane & 15;
  const int fq = lane >> 4;

  const int sr = tid >> 2;
  const int sc8 = (((tid & 3) ^ ((sr >> 1) & 3)) << 3);
  const unsigned short* Asrc  = h2 + ((size_t)(pos0 + sr)) * HALF_N + sc8;
  const unsigned short* Bsrc0 = w2b + ((size_t)e * K_DIM + n0 + sr) * HALF_N + sc8;
  const unsigned short* Bsrc1 = Bsrc0 + (size_t)128 * HALF_N;   // rows +128: key unchanged (128>>1 ≡ 0 mod 4)
  const int ldst = tid * 8;

  f32x4 acc[4][4];
  const f32x4 z = {0.f, 0.f, 0.f, 0.f};
#pragma unroll
  for (int i = 0; i < 4; ++i)
#pragma unroll
    for (int j = 0; j < 4; ++j) acc[i][j] = z;

  const int coff = ((fq ^ ((fr >> 1) & 3)) << 3);

  const int NT = HALF_N / 32;  // 88
  {
    gload_lds16(Asrc, &As[0][ldst]);
    gload_lds16(Bsrc0, &Bs[0][ldst]);
    gload_lds16(Bsrc1, &Bs[0][4096 + ldst]);
  }
  __syncthreads();

  for (int ht = 0; ht < NT; ++ht) {
    const int b = ht & 1;
    if (ht + 1 < NT) {
      const int k0 = (ht + 1) * 32;
      gload_lds16(Asrc + k0, &As[b ^ 1][ldst]);
      gload_lds16(Bsrc0 + k0, &Bs[b ^ 1][ldst]);
      gload_lds16(Bsrc1 + k0, &Bs[b ^ 1][4096 + ldst]);
    }
    s16x8 af[4], bf[4];
#pragma unroll
    for (int i = 0; i < 4; ++i)
      af[i] = *(const s16x8*)&As[b][(64 * wr + 16 * i + fr) * 32 + coff];
#pragma unroll
    for (int j = 0; j < 4; ++j)
      bf[j] = *(const s16x8*)&Bs[b][(64 * wc + 16 * j + fr) * 32 + coff];
#pragma unroll
    for (int i = 0; i < 4; ++i)
#pragma unroll
      for (int j = 0; j < 4; ++j)
        acc[i][j] = __builtin_amdgcn_mfma_f32_16x16x32_bf16(af[i], bf[j], acc[i][j], 0, 0, 0);
    __syncthreads();
  }

  const int vlim = eend - pos0;
#pragma unroll
  for (int i = 0; i < 4; ++i) {
#pragma unroll
    for (int rr = 0; rr < 4; ++rr) {
      const int row = 64 * wr + 16 * i + fq * 4 + rr;
      if (row < vlim) {
        const int pos = pos0 + row;
        const float wt = wgt[pos];
        unsigned short* dst = opair + (size_t)pos * K_DIM + n0 + 64 * wc;
#pragma unroll
        for (int j = 0; j < 4; ++j)
          dst[16 * j + fr] = (unsigned short)f2bf(wt * acc[i][j][rr]);
      }
    }
  }
}

// ---------------- combine: out[m] = opair[inv[2m]] + opair[inv[2m+1]] ----------------
__global__ void moe_combine(const unsigned short* __restrict__ opair,
                            const int* __restrict__ inv,
                            float* __restrict__ out) {
  const int m = blockIdx.x;
  const int t = threadIdx.x;  // 128 threads * 8 elems
  const int p0 = inv[2 * m], p1 = inv[2 * m + 1];
  const s16x8 a = *(const s16x8*)&opair[(size_t)p0 * K_DIM + t * 8];
  const s16x8 b = *(const s16x8*)&opair[(size_t)p1 * K_DIM + t * 8];
  f32x4 o0, o1;
  o0[0] = bf2f((unsigned short)a[0]) + bf2f((unsigned short)b[0]);
  o0[1] = bf2f((unsigned short)a[1]) + bf2f((unsigned short)b[1]);
  o0[2] = bf2f((unsigned short)a[2]) + bf2f((unsigned short)b[2]);
  o0[3] = bf2f((unsigned short)a[3]) + bf2f((unsigned short)b[3]);
  o1[0] = bf2f((unsigned short)a[4]) + bf2f((unsigned short)b[4]);
  o1[1] = bf2f((unsigned short)a[5]) + bf2f((unsigned short)b[5]);
  o1[2] = bf2f((unsigned short)a[6]) + bf2f((unsigned short)b[6]);
  o1[3] = bf2f((unsigned short)a[7]) + bf2f((unsigned short)b[7]);
  f32x4* dst = (f32x4*)(out + (size_t)m * K_DIM + t * 8);
  __builtin_nontemporal_store(o0, dst);       // final output, never re-read
  __builtin_nontemporal_store(o1, dst + 1);
}

__global__ void sentinel_k(float* o) { o[0] = 1.0e9f; }

extern "C" void kernel_launch(void* const* d_in, const int* in_sizes, int n_in,
                              void* d_out, int out_size, void* d_ws, size_t ws_size,
                              hipStream_t stream) {
  const float* hs = (const float*)d_in[0];
  const float* w1 = (const float*)d_in[1];
  const float* w2 = (const float*)d_in[2];
  const float* tw = (const float*)d_in[3];
  const int* ids = (const int*)d_in[4];
  float* out = (float*)d_out;

  char* p = (char*)d_ws;
  auto carve = [&](size_t bytes) {
    char* r = p;
    p += (bytes + 255) & ~(size_t)255;
    return r;
  };
  unsigned short* w1b = (unsigned short*)carve((size_t)E_NUM * N_DIM * K_DIM * 2);
  unsigned short* w2b = (unsigned short*)carve((size_t)E_NUM * K_DIM * HALF_N * 2);
  unsigned short* hsb = (unsigned short*)carve((size_t)(NPAIR + BM) * K_DIM * 2);
  unsigned short* h2  = (unsigned short*)carve((size_t)(NPAIR + BM) * HALF_N * 2);
  int*   tok  = (int*)carve(NPAIR * 4);
  float* wgt  = (float*)carve(NPAIR * 4);
  int*   inv  = (int*)carve(NPAIR * 4);
  int*   meta = (int*)carve(1024);
  int4*  desc = (int4*)carve(NDESC * sizeof(int4));
  size_t need = (size_t)(p - (char*)d_ws);

  // opair aliases hsb (hsb dead after gemm1; identical size NPAIR*K_DIM*2)
  unsigned short* opair = hsb;

  if (need > ws_size) {  // unmistakable failure mode if workspace is too small
    hipMemsetAsync(d_out, 0, (size_t)out_size * sizeof(float), stream);
    sentinel_k<<<1, 1, 0, stream>>>(out);
    return;
  }

  int* cnt  = meta;        // 8 ints
  int* fill = meta + 64;   // 8 ints
  int* offs = meta + 128;  // 9 ints

  hipMemsetAsync(meta, 0, 1024, stream);

  cvt_f32_bf16_k<<<2048, 256, 0, stream>>>(
      (const float4*)w1, (s16x4*)w1b, (int)((size_t)E_NUM * N_DIM * K_DIM / 4));
  cvt_f32_bf16_k<<<2048, 256, 0, stream>>>(
      (const float4*)w2, (s16x4*)w2b, (int)((size_t)E_NUM * K_DIM * HALF_N / 4));
  moe_count<<<NPAIR / 256, 256, 0, stream>>>(ids, cnt);
  moe_build<<<1, 64, 0, stream>>>(cnt, offs, desc);
  moe_scatter<<<NPAIR / 256, 256, 0, stream>>>(ids, tw, offs, fill, tok, wgt, inv);
  moe_gather<<<NPAIR, 128, 0, stream>>>(hs, tok, hsb);
  moe_gemm1<<<NHB1 * NDESC, 512, 0, stream>>>(hsb, w1b, desc, h2);
  moe_gemm2<<<NNB2 * NDESC, 512, 0, stream>>>(h2, w2b, desc, wgt, opair);
  moe_combine<<<M_TOK, 128, 0, stream>>>(opair, inv, out);
}

// Round 14
// 787.696 us; speedup vs baseline: 1.1109x; 1.0987x over previous
//
#include <hip/hip_runtime.h>
#include <hip/hip_bf16.h>

#define M_TOK 16384
#define K_DIM 1024
#define E_NUM 8
#define N_DIM 5632
#define HALF_N 2816
#define TOPK 2
#define NPAIR (M_TOK * TOPK)     // 32768
#define BM 128
#define BK 64
#define BH1 128                  // gemm1 h-cols per block
#define BN2 256                  // gemm2 k-cols per block
#define NDESC (NPAIR / BM + E_NUM)  // 264
#define NHB1 (HALF_N / BH1)      // 22
#define NNB2 (K_DIM / BN2)       // 4

typedef short s16x4 __attribute__((ext_vector_type(4)));
typedef short s16x8 __attribute__((ext_vector_type(8)));
typedef float f32x4 __attribute__((ext_vector_type(4)));

__device__ __forceinline__ short f2bf(float f) {
  union { __hip_bfloat16 h; short s; } c;
  c.h = __float2bfloat16(f);
  return c.s;
}

__device__ __forceinline__ float bf2f(unsigned short s) {
  union { float f; unsigned u; } c;
  c.u = ((unsigned)s) << 16;
  return c.f;
}

__device__ __forceinline__ void gload_lds16(const void* g, void* l) {
  __builtin_amdgcn_global_load_lds(
      (const __attribute__((address_space(1))) unsigned int*)g,
      (__attribute__((address_space(3))) unsigned int*)l, 16, 0, 0);
}

// bijective XCD-aware work remap (m204): consecutive work indices land on one XCD
__device__ __forceinline__ int xcd_work(int bid, int nwg) {
  const int xcd = bid & 7, loc = bid >> 3;
  const int q = nwg >> 3, r = nwg & 7;
  return (xcd < r ? xcd * (q + 1) : r * (q + 1) + (xcd - r) * q) + loc;
}

// ---------------- conversion ----------------
__global__ void cvt_f32_bf16_k(const float4* __restrict__ src,
                               s16x4* __restrict__ dst, int n4) {
  int i = blockIdx.x * blockDim.x + threadIdx.x;
  int stride = gridDim.x * blockDim.x;
  for (; i < n4; i += stride) {
    float4 f = src[i];
    s16x4 o = { f2bf(f.x), f2bf(f.y), f2bf(f.z), f2bf(f.w) };
    dst[i] = o;
  }
}

// ---------------- routing (two-level, ~1k global atomics total) ----------------
__global__ void moe_count(const int* __restrict__ ids, int* __restrict__ cnt) {
  const int p = blockIdx.x * 256 + threadIdx.x;
  const int e = ids[p];
  const int lane = threadIdx.x & 63;
  __shared__ int h[E_NUM];
  if (threadIdx.x < E_NUM) h[threadIdx.x] = 0;
  __syncthreads();
#pragma unroll
  for (int ex = 0; ex < E_NUM; ++ex) {
    unsigned long long m = __ballot(e == ex);
    if (lane == 0 && m) atomicAdd(&h[ex], __popcll(m));
  }
  __syncthreads();
  if (threadIdx.x < E_NUM) atomicAdd(&cnt[threadIdx.x], h[threadIdx.x]);
}

__global__ void moe_build(const int* __restrict__ cnt, int* __restrict__ offs,
                          int4* __restrict__ desc) {
  if (blockIdx.x == 0 && threadIdx.x == 0) {
    int o = 0, d = 0;
    for (int e = 0; e < E_NUM; ++e) {
      offs[e] = o;
      int end = o + cnt[e];
      for (int s = o; s < end; s += BM) desc[d++] = make_int4(e, s, end, 0);
      o = end;
    }
    offs[E_NUM] = o;
    while (d < NDESC) desc[d++] = make_int4(-1, 0, 0, 0);
  }
}

__global__ void moe_scatter(const int* __restrict__ ids, const float* __restrict__ tw,
                            const int* __restrict__ offs, int* __restrict__ fill,
                            int* __restrict__ tok, float* __restrict__ wgt,
                            int* __restrict__ inv) {
  const int p = blockIdx.x * 256 + threadIdx.x;
  const int e = ids[p];
  const int lane = threadIdx.x & 63;
  const int w = threadIdx.x >> 6;  // 0..3
  __shared__ int wcnt[4][E_NUM];
  __shared__ int wpre[4][E_NUM];
  __shared__ int base[E_NUM];
  const unsigned long long lt = (1ull << lane) - 1ull;
  int myrank = 0;
#pragma unroll
  for (int ex = 0; ex < E_NUM; ++ex) {
    unsigned long long m = __ballot(e == ex);
    if (e == ex) myrank = (int)__popcll(m & lt);
    if (lane == 0) wcnt[w][ex] = (int)__popcll(m);
  }
  __syncthreads();
  if (threadIdx.x < E_NUM) {
    const int ex = threadIdx.x;
    int s = 0;
#pragma unroll
    for (int ww = 0; ww < 4; ++ww) { wpre[ww][ex] = s; s += wcnt[ww][ex]; }
    base[ex] = atomicAdd(&fill[ex], s);
  }
  __syncthreads();
  const int pos = offs[e] + base[e] + wpre[w][e] + myrank;
  tok[pos] = p >> 1;
  wgt[pos] = tw[p];
  inv[p] = pos;
}

// gather hidden rows into expert-sorted order, fp32 -> bf16
__global__ void moe_gather(const float* __restrict__ hs, const int* __restrict__ tok,
                           unsigned short* __restrict__ hsb) {
  const int pos = blockIdx.x;
  const int m = tok[pos];
  const int t = threadIdx.x;  // 128 threads * 8 elems = 1024
  const float4* s = (const float4*)(hs + (size_t)m * K_DIM) + t * 2;
  const float4 a = s[0], b = s[1];
  s16x8 o = { f2bf(a.x), f2bf(a.y), f2bf(a.z), f2bf(a.w),
              f2bf(b.x), f2bf(b.y), f2bf(b.z), f2bf(b.w) };
  *(s16x8*)(hsb + (size_t)pos * K_DIM + t * 8) = o;
}

// ---------------- GEMM1: h2 = silu(A@Wg^T) * (A@Wu^T) ----------------
// round-7 proven kernel (desc-major decode) + nontemporal h2 stores (r11):
// the 180 MB write stream bypasses L2/L3 so the read set stays resident.
__launch_bounds__(512)
__global__ void moe_gemm1(const unsigned short* __restrict__ hsb,
                          const unsigned short* __restrict__ w1b,
                          const int4* __restrict__ desc,
                          unsigned short* __restrict__ h2) {
  const int work = xcd_work(blockIdx.x, NHB1 * NDESC);
  const int di = work / NHB1;    // desc-major (proven r7 mapping)
  const int hb = work - di * NHB1;
  const int4 d = desc[di];
  const int e = d.x;
  if (e < 0) return;
  const int pos0 = d.y, eend = d.z;
  const int h0 = hb * BH1;

  __shared__ __align__(16) unsigned short As[BM * BK];    // 16 KB
  __shared__ __align__(16) unsigned short Gs[BH1 * BK];   // 16 KB
  __shared__ __align__(16) unsigned short Us[BH1 * BK];   // 16 KB

  const int tid = threadIdx.x;
  const int lane = tid & 63;
  const int wid = tid >> 6;     // 0..7
  const int wr = wid >> 2;      // 0..1 (64-row group)
  const int wc = wid & 3;       // 0..3 (32-col group)

  const unsigned short* Ab = hsb + (size_t)pos0 * K_DIM;
  const unsigned short* Gb = w1b + ((size_t)e * N_DIM + h0) * K_DIM;
  const unsigned short* Ub = Gb + (size_t)HALF_N * K_DIM;

  f32x4 accg[4][2], accu[4][2];
  const f32x4 z = {0.f, 0.f, 0.f, 0.f};
#pragma unroll
  for (int i = 0; i < 4; ++i)
#pragma unroll
    for (int j = 0; j < 2; ++j) { accg[i][j] = z; accu[i][j] = z; }

  const int lrow = lane >> 3;                   // 0..7 row within segment
  const int scol = ((lane & 7) ^ lrow) << 3;    // swizzled source chunk (shorts)
  const int fr = lane & 15;
  const int fq = lane >> 4;
  const int sw = fr & 7;                        // read-side row swizzle key

  for (int kt = 0; kt < K_DIM / BK; ++kt) {
    const int k0 = kt * BK;
#pragma unroll
    for (int c = 0; c < 2; ++c) {
      const int seg = c * 8 + wid;              // 0..15
      const int row = seg * 8 + lrow;
      gload_lds16(Ab + (size_t)row * K_DIM + k0 + scol, &As[seg * 512]);
      gload_lds16(Gb + (size_t)row * K_DIM + k0 + scol, &Gs[seg * 512]);
      gload_lds16(Ub + (size_t)row * K_DIM + k0 + scol, &Us[seg * 512]);
    }
    __syncthreads();
#pragma unroll
    for (int s = 0; s < 2; ++s) {
      const int coff = (((s * 4 + fq) ^ sw) << 3);
      s16x8 af[4];
#pragma unroll
      for (int i = 0; i < 4; ++i)
        af[i] = *(const s16x8*)&As[(64 * wr + 16 * i + fr) * BK + coff];
      s16x8 gf[2], uf[2];
#pragma unroll
      for (int j = 0; j < 2; ++j) {
        const int hr = (32 * wc + 16 * j + fr) * BK + coff;
        gf[j] = *(const s16x8*)&Gs[hr];
        uf[j] = *(const s16x8*)&Us[hr];
      }
#pragma unroll
      for (int i = 0; i < 4; ++i)
#pragma unroll
        for (int j = 0; j < 2; ++j) {
          accg[i][j] = __builtin_amdgcn_mfma_f32_16x16x32_bf16(af[i], gf[j], accg[i][j], 0, 0, 0);
          accu[i][j] = __builtin_amdgcn_mfma_f32_16x16x32_bf16(af[i], uf[j], accu[i][j], 0, 0, 0);
        }
    }
    __syncthreads();
  }

  const int vlim = eend - pos0;
#pragma unroll
  for (int i = 0; i < 4; ++i) {
#pragma unroll
    for (int rr = 0; rr < 4; ++rr) {
      const int row = 64 * wr + 16 * i + fq * 4 + rr;
      if (row < vlim) {
        unsigned short* dst = h2 + (size_t)(pos0 + row) * HALF_N + h0 + 32 * wc;
#pragma unroll
        for (int j = 0; j < 2; ++j) {
          const float g = accg[i][j][rr];
          const float u = accu[i][j][rr];
          const float sg = g / (1.0f + __expf(-g));
          __builtin_nontemporal_store((unsigned short)f2bf(sg * u), dst + 16 * j + fr);
        }
      }
    }
  }
}

// ---------------- GEMM2: opair[pos] = wgt[pos] * (h2[pos] @ W2^T) ----------------
// round-7 proven kernel, desc-major decode. opair stores stay normal (combine
// reads them right after -> L3 residency is useful).
__launch_bounds__(512)
__global__ void moe_gemm2(const unsigned short* __restrict__ h2,
                          const unsigned short* __restrict__ w2b,
                          const int4* __restrict__ desc,
                          const float* __restrict__ wgt,
                          unsigned short* __restrict__ opair) {
  const int work = xcd_work(blockIdx.x, NNB2 * NDESC);
  const int di = work >> 2;      // desc-major (proven r7 mapping)
  const int nb = work & 3;
  const int4 d = desc[di];
  const int e = d.x;
  if (e < 0) return;
  const int pos0 = d.y, eend = d.z;
  const int n0 = nb * BN2;

  __shared__ __align__(16) unsigned short As[BM * BK];    // 16 KB
  __shared__ __align__(16) unsigned short Bs[BN2 * BK];   // 32 KB

  const int tid = threadIdx.x;
  const int lane = tid & 63;
  const int wid = tid >> 6;     // 0..7
  const int wr = wid >> 2;      // 0..1 (64-row group)
  const int wc = wid & 3;       // 0..3 (64-col group)

  const unsigned short* Ab = h2 + (size_t)pos0 * HALF_N;
  const unsigned short* Bb = w2b + ((size_t)e * K_DIM + n0) * HALF_N;

  f32x4 acc[4][4];
  const f32x4 z = {0.f, 0.f, 0.f, 0.f};
#pragma unroll
  for (int i = 0; i < 4; ++i)
#pragma unroll
    for (int j = 0; j < 4; ++j) acc[i][j] = z;

  const int lrow = lane >> 3;
  const int scol = ((lane & 7) ^ lrow) << 3;
  const int fr = lane & 15;
  const int fq = lane >> 4;
  const int sw = fr & 7;

  for (int ht = 0; ht < HALF_N / BK; ++ht) {   // 44
    const int k0 = ht * BK;
#pragma unroll
    for (int c = 0; c < 2; ++c) {
      const int seg = c * 8 + wid;             // 0..15
      const int row = seg * 8 + lrow;
      gload_lds16(Ab + (size_t)row * HALF_N + k0 + scol, &As[seg * 512]);
    }
#pragma unroll
    for (int c = 0; c < 4; ++c) {
      const int seg = c * 8 + wid;             // 0..31
      const int row = seg * 8 + lrow;
      gload_lds16(Bb + (size_t)row * HALF_N + k0 + scol, &Bs[seg * 512]);
    }
    __syncthreads();
#pragma unroll
    for (int s = 0; s < 2; ++s) {
      const int coff = (((s * 4 + fq) ^ sw) << 3);
      s16x8 af[4], bf[4];
#pragma unroll
      for (int i = 0; i < 4; ++i)
        af[i] = *(const s16x8*)&As[(64 * wr + 16 * i + fr) * BK + coff];
#pragma unroll
      for (int j = 0; j < 4; ++j)
        bf[j] = *(const s16x8*)&Bs[(64 * wc + 16 * j + fr) * BK + coff];
#pragma unroll
      for (int i = 0; i < 4; ++i)
#pragma unroll
        for (int j = 0; j < 4; ++j)
          acc[i][j] = __builtin_amdgcn_mfma_f32_16x16x32_bf16(af[i], bf[j], acc[i][j], 0, 0, 0);
    }
    __syncthreads();
  }

  const int vlim = eend - pos0;
#pragma unroll
  for (int i = 0; i < 4; ++i) {
#pragma unroll
    for (int rr = 0; rr < 4; ++rr) {
      const int row = 64 * wr + 16 * i + fq * 4 + rr;
      if (row < vlim) {
        const int pos = pos0 + row;
        const float wt = wgt[pos];
        unsigned short* dst = opair + (size_t)pos * K_DIM + n0 + 64 * wc;
#pragma unroll
        for (int j = 0; j < 4; ++j)
          dst[16 * j + fr] = (unsigned short)f2bf(wt * acc[i][j][rr]);
      }
    }
  }
}

// ---------------- combine: out[m] = opair[inv[2m]] + opair[inv[2m+1]] ----------------
__global__ void moe_combine(const unsigned short* __restrict__ opair,
                            const int* __restrict__ inv,
                            float* __restrict__ out) {
  const int m = blockIdx.x;
  const int t = threadIdx.x;  // 128 threads * 8 elems
  const int p0 = inv[2 * m], p1 = inv[2 * m + 1];
  const s16x8 a = *(const s16x8*)&opair[(size_t)p0 * K_DIM + t * 8];
  const s16x8 b = *(const s16x8*)&opair[(size_t)p1 * K_DIM + t * 8];
  f32x4 o0, o1;
  o0[0] = bf2f((unsigned short)a[0]) + bf2f((unsigned short)b[0]);
  o0[1] = bf2f((unsigned short)a[1]) + bf2f((unsigned short)b[1]);
  o0[2] = bf2f((unsigned short)a[2]) + bf2f((unsigned short)b[2]);
  o0[3] = bf2f((unsigned short)a[3]) + bf2f((unsigned short)b[3]);
  o1[0] = bf2f((unsigned short)a[4]) + bf2f((unsigned short)b[4]);
  o1[1] = bf2f((unsigned short)a[5]) + bf2f((unsigned short)b[5]);
  o1[2] = bf2f((unsigned short)a[6]) + bf2f((unsigned short)b[6]);
  o1[3] = bf2f((unsigned short)a[7]) + bf2f((unsigned short)b[7]);
  f32x4* dst = (f32x4*)(out + (size_t)m * K_DIM + t * 8);
  __builtin_nontemporal_store(o0, dst);       // final output, never re-read
  __builtin_nontemporal_store(o1, dst + 1);
}

__global__ void sentinel_k(float* o) { o[0] = 1.0e9f; }

extern "C" void kernel_launch(void* const* d_in, const int* in_sizes, int n_in,
                              void* d_out, int out_size, void* d_ws, size_t ws_size,
                              hipStream_t stream) {
  const float* hs = (const float*)d_in[0];
  const float* w1 = (const float*)d_in[1];
  const float* w2 = (const float*)d_in[2];
  const float* tw = (const float*)d_in[3];
  const int* ids = (const int*)d_in[4];
  float* out = (float*)d_out;

  char* p = (char*)d_ws;
  auto carve = [&](size_t bytes) {
    char* r = p;
    p += (bytes + 255) & ~(size_t)255;
    return r;
  };
  unsigned short* w1b = (unsigned short*)carve((size_t)E_NUM * N_DIM * K_DIM * 2);
  unsigned short* w2b = (unsigned short*)carve((size_t)E_NUM * K_DIM * HALF_N * 2);
  unsigned short* hsb = (unsigned short*)carve((size_t)(NPAIR + BM) * K_DIM * 2);
  unsigned short* h2  = (unsigned short*)carve((size_t)(NPAIR + BM) * HALF_N * 2);
  int*   tok  = (int*)carve(NPAIR * 4);
  float* wgt  = (float*)carve(NPAIR * 4);
  int*   inv  = (int*)carve(NPAIR * 4);
  int*   meta = (int*)carve(1024);
  int4*  desc = (int4*)carve(NDESC * sizeof(int4));
  size_t need = (size_t)(p - (char*)d_ws);

  // opair aliases hsb (hsb dead after gemm1; identical size NPAIR*K_DIM*2)
  unsigned short* opair = hsb;

  if (need > ws_size) {  // unmistakable failure mode if workspace is too small
    hipMemsetAsync(d_out, 0, (size_t)out_size * sizeof(float), stream);
    sentinel_k<<<1, 1, 0, stream>>>(out);
    return;
  }

  int* cnt  = meta;        // 8 ints
  int* fill = meta + 64;   // 8 ints
  int* offs = meta + 128;  // 9 ints

  hipMemsetAsync(meta, 0, 1024, stream);

  cvt_f32_bf16_k<<<2048, 256, 0, stream>>>(
      (const float4*)w1, (s16x4*)w1b, (int)((size_t)E_NUM * N_DIM * K_DIM / 4));
  cvt_f32_bf16_k<<<2048, 256, 0, stream>>>(
      (const float4*)w2, (s16x4*)w2b, (int)((size_t)E_NUM * K_DIM * HALF_N / 4));
  moe_count<<<NPAIR / 256, 256, 0, stream>>>(ids, cnt);
  moe_build<<<1, 64, 0, stream>>>(cnt, offs, desc);
  moe_scatter<<<NPAIR / 256, 256, 0, stream>>>(ids, tw, offs, fill, tok, wgt, inv);
  moe_gather<<<NPAIR, 128, 0, stream>>>(hs, tok, hsb);
  moe_gemm1<<<NHB1 * NDESC, 512, 0, stream>>>(hsb, w1b, desc, h2);
  moe_gemm2<<<NNB2 * NDESC, 512, 0, stream>>>(h2, w2b, desc, wgt, opair);
  moe_combine<<<M_TOK, 128, 0, stream>>>(opair, inv, out);
}